// Round 9
// baseline (221.977 us; speedup 1.0000x reference)
//
#include <hip/hip_runtime.h>
#include <hip/hip_bf16.h>
#include <cstddef>

// Dims fixed by reference: B=2, S=2048, H=1024, NH=4, DH=256
constexpr int Bx = 2, Sx = 2048, Hx = 1024, NHx = 4, DHx = 256;
constexpr float RSQ = 0.0625f;   // 1/sqrt(256)

typedef __attribute__((ext_vector_type(8))) short    bf16x8;
typedef __attribute__((ext_vector_type(4))) float    f32x4;
typedef __attribute__((ext_vector_type(4))) unsigned u32x4;

__device__ __forceinline__ float logsigf(float x) {
  return (x >= 0.0f) ? -log1pf(expf(-x)) : x - log1pf(expf(x));
}
__device__ __forceinline__ unsigned short f2bf(float x) {  // RNE f32->bf16
  unsigned u = __builtin_bit_cast(unsigned, x);
  u = (u + 0x7fffu + ((u >> 16) & 1u)) >> 16;
  return (unsigned short)u;
}
__device__ __forceinline__ unsigned pk2bf(float a, float b) {
  return (unsigned)f2bf(a) | ((unsigned)f2bf(b) << 16);
}

// ---------- K1: gates (ig/fg) + bf16 side-copies of Q,K ---------------------
__global__ __launch_bounds__(512)
void gates_kernel(const float* __restrict__ q, const float* __restrict__ k,
                  const float* __restrict__ v,
                  const float* __restrict__ wi, const float* __restrict__ bi,
                  const float* __restrict__ wf, const float* __restrict__ bf,
                  float* __restrict__ ig, float* __restrict__ fg,
                  unsigned short* __restrict__ Qb, unsigned short* __restrict__ Kb)
{
  const int w = threadIdx.x >> 6, l = threadIdx.x & 63;
  const int bs0 = blockIdx.x * 16;
  const int bsr0 = bs0 + w * 2, bsr1 = bsr0 + 1;
  float p[2][8];
#pragma unroll
  for (int rr = 0; rr < 2; ++rr)
#pragma unroll
    for (int g2 = 0; g2 < 8; ++g2) p[rr][g2] = 0.f;

#pragma unroll
  for (int chunk = 0; chunk < 12; ++chunk) {
    const int idx = l * 4 + chunk * 256;     // 0..3071
    const float* src; int off;
    if (idx < 1024)       { src = q; off = idx; }
    else if (idx < 2048)  { src = k; off = idx - 1024; }
    else                  { src = v; off = idx - 2048; }
    float4 g0 = *(const float4*)(src + (size_t)bsr0 * Hx + off);
    float4 g1 = *(const float4*)(src + (size_t)bsr1 * Hx + off);
#pragma unroll
    for (int h = 0; h < 4; ++h) {
      float4 wiv = *(const float4*)(wi + h * 3 * Hx + idx);
      float4 wfv = *(const float4*)(wf + h * 3 * Hx + idx);
      p[0][h]     += g0.x*wiv.x + g0.y*wiv.y + g0.z*wiv.z + g0.w*wiv.w;
      p[1][h]     += g1.x*wiv.x + g1.y*wiv.y + g1.z*wiv.z + g1.w*wiv.w;
      p[0][4 + h] += g0.x*wfv.x + g0.y*wfv.y + g0.z*wfv.z + g0.w*wfv.w;
      p[1][4 + h] += g1.x*wfv.x + g1.y*wfv.y + g1.z*wfv.z + g1.w*wfv.w;
    }
    if (idx < 2048) {
      unsigned short* dst = (idx < 1024) ? Qb : Kb;
      const int hh = off >> 8, d = off & 255;
      const int b0 = bsr0 >> 11, s0p = bsr0 & 2047;
      const int b1 = bsr1 >> 11, s1p = bsr1 & 2047;
      ushort4 o0; o0.x=f2bf(g0.x); o0.y=f2bf(g0.y); o0.z=f2bf(g0.z); o0.w=f2bf(g0.w);
      ushort4 o1; o1.x=f2bf(g1.x); o1.y=f2bf(g1.y); o1.z=f2bf(g1.z); o1.w=f2bf(g1.w);
      *(ushort4*)(dst + ((size_t)(b0 * NHx + hh) * Sx + s0p) * DHx + d) = o0;
      *(ushort4*)(dst + ((size_t)(b1 * NHx + hh) * Sx + s1p) * DHx + d) = o1;
    }
  }
#pragma unroll
  for (int rr = 0; rr < 2; ++rr)
#pragma unroll
    for (int g2 = 0; g2 < 8; ++g2) {
      float x = p[rr][g2];
      x += __shfl_xor(x, 1);  x += __shfl_xor(x, 2);  x += __shfl_xor(x, 4);
      x += __shfl_xor(x, 8);  x += __shfl_xor(x, 16); x += __shfl_xor(x, 32);
      p[rr][g2] = x;
    }
  if (l == 0) {
#pragma unroll
    for (int rr = 0; rr < 2; ++rr) {
      const int bs = bs0 + w * 2 + rr;
      const int b = bs >> 11, spos = bs & 2047;
#pragma unroll
      for (int h = 0; h < 4; ++h) {
        ig[(size_t)(b * NHx + h) * Sx + spos] = p[rr][h] + bi[h];
        fg[(size_t)(b * NHx + h) * Sx + spos] = p[rr][4 + h] + bf[h];
      }
    }
  }
}

// ---------- K2: per-(b,h) scan: a[], M[], exp(-m)[] -------------------------
__global__ __launch_bounds__(256)
void scan_kernel(const float* __restrict__ ig, const float* __restrict__ fg,
                 float* __restrict__ av, float* __restrict__ Mv,
                 float* __restrict__ nfv)
{
  const int bh = blockIdx.x;
  const int t  = threadIdx.x;
  const size_t base = (size_t)bh * Sx;
  const int s0 = t * 8;
  float4 f0 = *(const float4*)(fg + base + s0);
  float4 f1 = *(const float4*)(fg + base + s0 + 4);
  float4 g0 = *(const float4*)(ig + base + s0);
  float4 g1 = *(const float4*)(ig + base + s0 + 4);
  float xf[8] = {f0.x,f0.y,f0.z,f0.w,f1.x,f1.y,f1.z,f1.w};
  float xi[8] = {g0.x,g0.y,g0.z,g0.w,g1.x,g1.y,g1.z,g1.w};
  float ps[8];
  float run = 0.0f;
#pragma unroll
  for (int i = 0; i < 8; ++i) { run += logsigf(xf[i]); ps[i] = run; }
  __shared__ float ssum[256];
  __shared__ float smax[256];
  ssum[t] = run;
  __syncthreads();
  for (int st = 1; st < 256; st <<= 1) {
    float addv = (t >= st) ? ssum[t - st] : 0.0f;
    __syncthreads();
    ssum[t] += addv;
    __syncthreads();
  }
  const float exs = (t > 0) ? ssum[t - 1] : 0.0f;
  float a[8], pm[8];
  float rm = -INFINITY;
#pragma unroll
  for (int i = 0; i < 8; ++i) {
    a[i] = xi[i] - (exs + ps[i]);
    rm = fmaxf(rm, a[i]);
    pm[i] = rm;
  }
  smax[t] = rm;
  __syncthreads();
  for (int st = 1; st < 256; st <<= 1) {
    float mv = (t >= st) ? smax[t - st] : -INFINITY;
    __syncthreads();
    smax[t] = fmaxf(smax[t], mv);
    __syncthreads();
  }
  const float exm = (t > 0) ? smax[t - 1] : -INFINITY;
#pragma unroll
  for (int i = 0; i < 8; ++i) {
    const float M = fmaxf(exm, pm[i]);
    const float F = exs + ps[i];
    av[base + s0 + i]  = a[i];
    Mv[base + s0 + i]  = M;
    nfv[base + s0 + i] = expf(-(F + M));
  }
}

// ---------- K3: V -> bf16 transposed global Vt[bh][d][s] --------------------
__global__ __launch_bounds__(256)
void vtrans_kernel(const float* __restrict__ v, unsigned short* __restrict__ vt)
{
  __shared__ float tile[64][68];
  const int st0 = blockIdx.x * 64, dt0 = blockIdx.y * 64;
  const int bh = blockIdx.z, b = bh >> 2, h = bh & 3;
  const int t = threadIdx.x;
#pragma unroll
  for (int i = 0; i < 4; ++i) {
    int u = t + 256 * i;
    int r = u >> 4, c4 = (u & 15) * 4;
    const float* p = v + ((size_t)(b * Sx) + st0 + r) * Hx + h * DHx + dt0 + c4;
    float4 vv = *(const float4*)p;
    tile[r][c4] = vv.x; tile[r][c4+1] = vv.y; tile[r][c4+2] = vv.z; tile[r][c4+3] = vv.w;
  }
  __syncthreads();
#pragma unroll
  for (int i = 0; i < 4; ++i) {
    int u = t + 256 * i;
    int dr = u >> 4, c4 = (u & 15) * 4;
    ushort4 o;
    o.x = f2bf(tile[c4+0][dr]); o.y = f2bf(tile[c4+1][dr]);
    o.z = f2bf(tile[c4+2][dr]); o.w = f2bf(tile[c4+3][dr]);
    *(ushort4*)(vt + ((size_t)bh * DHx + dt0 + dr) * Sx + st0 + c4) = o;
  }
}

// ---------- K4a: pass 1 — chunked flash partials (barrier-free, 1 wave) ------
// Unit = (bh, q-tile of 16 rows, 512-key chunk). 2560 units total.
// Partials: O (16x256 f32) + rsum(16) per unit, combined exactly in pass 2
// (valid because M[i] is a global precomputed max -> no rescaling needed).
__global__ __launch_bounds__(64, 2)
void mlstm_pass1(const unsigned short* __restrict__ Qb,
                 const unsigned short* __restrict__ Kb,
                 const unsigned short* __restrict__ Vt,
                 const float* __restrict__ av, const float* __restrict__ Mv,
                 float* __restrict__ part)
{
  const int bh = blockIdx.x;
  const int u = 319 - (int)blockIdx.y;            // big chunks first (LPT)
  int ti, c;
  if (u < 32)       { ti = u;                  c = 0; }
  else if (u < 96)  { ti = 32 + ((u - 32) >> 1);  c = (u - 32) & 1; }
  else if (u < 192) { ti = 64 + (u - 96) / 3;     c = (u - 96) % 3; }
  else              { ti = 96 + ((u - 192) >> 2); c = (u - 192) & 3; }
  const int G = ti >> 5, R = ti & 31;
  const int pidx = bh * 320 + (ti + 16 * G * (G - 1) + R * G) + c;

  const int i0 = ti * 16;
  const int l = threadIdx.x, lg = l >> 4, ll = l & 15;
  const size_t bhS = (size_t)bh * Sx;
  const int qrow = i0 + ll;

  bf16x8 qf[8];
  {
    const unsigned short* qp = Qb + (bhS + qrow) * DHx + lg * 8;
#pragma unroll
    for (int d8 = 0; d8 < 8; ++d8) qf[d8] = *(const bf16x8*)(qp + d8 * 32);
  }
  const float Mq = Mv[bhS + qrow];

  f32x4 acc[16];
#pragma unroll
  for (int jt = 0; jt < 16; ++jt) acc[jt] = f32x4{0, 0, 0, 0};
  float rsum = 0.f;

  const int tj0 = c * 16;
  const int ntot = (i0 + 47) >> 5;                // ceil((i0+16)/32)
  const int tjE = (tj0 + 16 < ntot) ? tj0 + 16 : ntot;

  const unsigned short* kb0 = Kb + (bhS + ll) * DHx + lg * 8;
  const unsigned short* vb0 = Vt + ((size_t)bh * DHx + ll) * Sx + lg * 8;

  for (int tj = tj0; tj < tjE; ++tj) {
    const int j0 = tj * 32;
    // ---- issue K frags (32 keys) + V frags dsub 0..7 ----
    const unsigned short* kp = kb0 + (size_t)j0 * DHx;
    bf16x8 kf0[8], kf1[8];
#pragma unroll
    for (int d8 = 0; d8 < 8; ++d8) {
      kf0[d8] = *(const bf16x8*)(kp + d8 * 32);
      kf1[d8] = *(const bf16x8*)(kp + 16 * DHx + d8 * 32);
    }
    bf16x8 vfA[8];
#pragma unroll
    for (int ds = 0; ds < 8; ++ds)
      vfA[ds] = *(const bf16x8*)(vb0 + (size_t)(ds * 16) * Sx + j0);
    const f32x4 a4_0 = *(const f32x4*)(av + bhS + j0 + lg * 4);
    const f32x4 a4_1 = *(const f32x4*)(av + bhS + j0 + 16 + lg * 4);

    // ---- QK: two 16-key subtiles, split dependency chains ----
    f32x4 s0a = {0,0,0,0}, s0b = {0,0,0,0}, s1a = {0,0,0,0}, s1b = {0,0,0,0};
#pragma unroll
    for (int d8 = 0; d8 < 4; ++d8) {
      s0a = __builtin_amdgcn_mfma_f32_16x16x32_bf16(kf0[d8], qf[d8], s0a, 0, 0, 0);
      s1a = __builtin_amdgcn_mfma_f32_16x16x32_bf16(kf1[d8], qf[d8], s1a, 0, 0, 0);
    }
#pragma unroll
    for (int d8 = 4; d8 < 8; ++d8) {
      s0b = __builtin_amdgcn_mfma_f32_16x16x32_bf16(kf0[d8], qf[d8], s0b, 0, 0, 0);
      s1b = __builtin_amdgcn_mfma_f32_16x16x32_bf16(kf1[d8], qf[d8], s1b, 0, 0, 0);
    }
    const f32x4 st0 = s0a + s0b;
    const f32x4 st1 = s1a + s1b;

    // ---- issue V frags dsub 8..15 (land during transform) ----
    bf16x8 vfB[8];
#pragma unroll
    for (int ds = 0; ds < 8; ++ds)
      vfB[ds] = *(const bf16x8*)(vb0 + (size_t)((ds + 8) * 16) * Sx + j0);

    // ---- transform: mask + decay + rsum; pack bf16; lane redistribution ----
    unsigned x0[4], x1[4];
#pragma unroll
    for (int kt = 0; kt < 2; ++kt) {
      const f32x4 s = kt ? st1 : st0;
      const f32x4 a = kt ? a4_1 : a4_0;
      const int kb = j0 + kt * 16 + 4 * lg;
      float p0 = (kb + 0 <= qrow) ? s[0] * (RSQ * __expf(a[0] - Mq)) : 0.f;
      float p1 = (kb + 1 <= qrow) ? s[1] * (RSQ * __expf(a[1] - Mq)) : 0.f;
      float p2 = (kb + 2 <= qrow) ? s[2] * (RSQ * __expf(a[2] - Mq)) : 0.f;
      float p3 = (kb + 3 <= qrow) ? s[3] * (RSQ * __expf(a[3] - Mq)) : 0.f;
      rsum += (p0 + p1) + (p2 + p3);
      unsigned lo = pk2bf(p0, p1), hi = pk2bf(p2, p3);
      unsigned plo = __shfl_xor(lo, 16), phi = __shfl_xor(hi, 16);
      bool ge = ((lg & 1) == 0);
      unsigned* x = kt ? x1 : x0;
      x[0] = ge ? lo : plo;  x[1] = ge ? hi : phi;
      x[2] = ge ? plo : lo;  x[3] = ge ? phi : hi;
    }
    unsigned pw0, pw1, pw2, pw3;
#pragma unroll
    for (int j = 0; j < 4; ++j) {
      unsigned yA = __shfl_xor(x0[j], 32);
      unsigned yB = __shfl_xor(x1[j], 32);
      unsigned r = (lg == 0) ? x0[j] : (lg == 1) ? yA : (lg == 2) ? yB : x1[j];
      if (j == 0) pw0 = r; else if (j == 1) pw1 = r; else if (j == 2) pw2 = r; else pw3 = r;
    }
    u32x4 w4 = {pw0, pw1, pw2, pw3};
    bf16x8 pb = __builtin_bit_cast(bf16x8, w4);

    // ---- PV ----
#pragma unroll
    for (int ds = 0; ds < 8; ++ds)
      acc[ds] = __builtin_amdgcn_mfma_f32_16x16x32_bf16(vfA[ds], pb, acc[ds], 0, 0, 0);
#pragma unroll
    for (int ds = 0; ds < 8; ++ds)
      acc[8 + ds] = __builtin_amdgcn_mfma_f32_16x16x32_bf16(vfB[ds], pb, acc[8 + ds], 0, 0, 0);
  }

  // ---- store partials: O (16x256) + rsum(16) ----
  float* pO = part + (size_t)pidx * 4112;
#pragma unroll
  for (int jt = 0; jt < 16; ++jt)
    *(f32x4*)(pO + ll * 256 + jt * 16 + lg * 4) = acc[jt];
  float rs = rsum;
  rs += __shfl_xor(rs, 16); rs += __shfl_xor(rs, 32);
  if (l < 16) pO[4096 + ll] = rs;
}

// ---------- K4b: pass 2 — combine partials + normalizer + group-LN ----------
__global__ __launch_bounds__(256)
void mlstm_pass2(const float* __restrict__ part, const float* __restrict__ nfv,
                 const float* __restrict__ lnw, float* __restrict__ out)
{
  const int bh = blockIdx.x, b = bh >> 2, h = bh & 3;
  const int ti = blockIdx.y;
  const int nc = (ti >> 5) + 1;
  const int G = ti >> 5, R = ti & 31;
  const int p0 = bh * 320 + ti + 16 * G * (G - 1) + R * G;
  const int t = threadIdx.x, q = t >> 4, dc = (t & 15) * 16;
  const size_t bhS = (size_t)bh * Sx;
  const int qrow = ti * 16 + q;

  f32x4 o[4];
#pragma unroll
  for (int j = 0; j < 4; ++j) o[j] = f32x4{0, 0, 0, 0};
  float rs = 0.f;
  for (int cc = 0; cc < nc; ++cc) {
    const float* pO = part + (size_t)(p0 + cc) * 4112;
    const float* pq = pO + q * 256 + dc;
#pragma unroll
    for (int j = 0; j < 4; ++j) o[j] += *(const f32x4*)(pq + j * 4);
    rs += pO[4096 + q];
  }
  float s1 = 0.f, s2 = 0.f;
#pragma unroll
  for (int j = 0; j < 4; ++j)
#pragma unroll
    for (int r = 0; r < 4; ++r) {
      const float x = o[j][r];
      s1 += x; s2 += x * x;
    }
  s1 += __shfl_xor(s1, 1); s1 += __shfl_xor(s1, 2);
  s1 += __shfl_xor(s1, 4); s1 += __shfl_xor(s1, 8);
  s2 += __shfl_xor(s2, 1); s2 += __shfl_xor(s2, 2);
  s2 += __shfl_xor(s2, 4); s2 += __shfl_xor(s2, 8);

  const float nf = nfv[bhS + qrow];
  const float inv = 1.f / (fmaxf(fabsf(rs), nf) + 1e-6f);
  const float mean = s1 * inv * (1.f / 256.f);
  const float ex2  = s2 * inv * inv * (1.f / 256.f);
  const float var  = ex2 - mean * mean;
  const float rstd = rsqrtf(var + 1e-5f);
  float* op = out + ((size_t)b * Sx + qrow) * Hx + h * DHx + dc;
#pragma unroll
  for (int j = 0; j < 4; ++j) {
    f32x4 lw = *(const f32x4*)(lnw + h * DHx + dc + j * 4);
    float4 ov;
    ov.x = (o[j][0] * inv - mean) * rstd * (1.f + lw[0]);
    ov.y = (o[j][1] * inv - mean) * rstd * (1.f + lw[1]);
    ov.z = (o[j][2] * inv - mean) * rstd * (1.f + lw[2]);
    ov.w = (o[j][3] * inv - mean) * rstd * (1.f + lw[3]);
    *(float4*)(op + j * 4) = ov;
  }
}

extern "C" void kernel_launch(void* const* d_in, const int* in_sizes, int n_in,
                              void* d_out, int out_size, void* d_ws, size_t ws_size,
                              hipStream_t stream) {
  const float* q   = (const float*)d_in[0];
  const float* k   = (const float*)d_in[1];
  const float* v   = (const float*)d_in[2];
  const float* wi  = (const float*)d_in[3];
  const float* bi  = (const float*)d_in[4];
  const float* wf  = (const float*)d_in[5];
  const float* bf  = (const float*)d_in[6];
  const float* lnw = (const float*)d_in[7];
  float* out = (float*)d_out;
  float* ws  = (float*)d_ws;

  const int G = Bx * NHx * Sx;         // 16384
  float* ig  = ws;
  float* fg  = ws + (size_t)G;
  float* av  = ws + (size_t)2 * G;
  float* Mv  = ws + (size_t)3 * G;
  float* nfv = ws + (size_t)4 * G;
  unsigned short* Qb = (unsigned short*)(ws + (size_t)5 * G);
  unsigned short* Kb = Qb + (size_t)Bx * Sx * Hx;   // 4,194,304 elems
  unsigned short* Vt = Kb + (size_t)Bx * Sx * Hx;
  float* part = (float*)(Vt + (size_t)Bx * Sx * Hx); // 2560 x 4112 f32 = 42.1 MB
  // total ws use: ~67.6 MB

  gates_kernel<<<Bx * Sx / 16, 512, 0, stream>>>(q, k, v, wi, bi, wf, bf, ig, fg, Qb, Kb);
  scan_kernel<<<Bx * NHx, 256, 0, stream>>>(ig, fg, av, Mv, nfv);
  dim3 gT(Sx / 64, DHx / 64, Bx * NHx);
  vtrans_kernel<<<gT, 256, 0, stream>>>(v, Vt);
  dim3 g1(Bx * NHx, 320);              // x = bh (XCD pinned), y = unit
  mlstm_pass1<<<g1, 64, 0, stream>>>(Qb, Kb, Vt, av, Mv, part);
  dim3 g2(Bx * NHx, Sx / 16);
  mlstm_pass2<<<g2, 256, 0, stream>>>(part, nfv, lnw, out);
}

// Round 10
// 210.885 us; speedup vs baseline: 1.0526x; 1.0526x over previous
//
#include <hip/hip_runtime.h>
#include <hip/hip_bf16.h>
#include <cstddef>

// Dims fixed by reference: B=2, S=2048, H=1024, NH=4, DH=256
constexpr int Bx = 2, Sx = 2048, Hx = 1024, NHx = 4, DHx = 256;
constexpr float RSQ = 0.0625f;   // 1/sqrt(256)

typedef __attribute__((ext_vector_type(8))) short    bf16x8;
typedef __attribute__((ext_vector_type(4))) float    f32x4;
typedef __attribute__((ext_vector_type(4))) unsigned u32x4;

__device__ __forceinline__ float logsigf(float x) {
  return (x >= 0.0f) ? -log1pf(expf(-x)) : x - log1pf(expf(x));
}
__device__ __forceinline__ unsigned short f2bf(float x) {  // RNE f32->bf16
  unsigned u = __builtin_bit_cast(unsigned, x);
  u = (u + 0x7fffu + ((u >> 16) & 1u)) >> 16;
  return (unsigned short)u;
}
__device__ __forceinline__ unsigned pk2bf(float a, float b) {
  return (unsigned)f2bf(a) | ((unsigned)f2bf(b) << 16);
}

// ---------- K1: gates (ig/fg) + bf16 side-copies of Q,K ---------------------
__global__ __launch_bounds__(512)
void gates_kernel(const float* __restrict__ q, const float* __restrict__ k,
                  const float* __restrict__ v,
                  const float* __restrict__ wi, const float* __restrict__ bi,
                  const float* __restrict__ wf, const float* __restrict__ bf,
                  float* __restrict__ ig, float* __restrict__ fg,
                  unsigned short* __restrict__ Qb, unsigned short* __restrict__ Kb)
{
  const int w = threadIdx.x >> 6, l = threadIdx.x & 63;
  const int bs0 = blockIdx.x * 16;
  const int bsr0 = bs0 + w * 2, bsr1 = bsr0 + 1;
  float p[2][8];
#pragma unroll
  for (int rr = 0; rr < 2; ++rr)
#pragma unroll
    for (int g2 = 0; g2 < 8; ++g2) p[rr][g2] = 0.f;

#pragma unroll
  for (int chunk = 0; chunk < 12; ++chunk) {
    const int idx = l * 4 + chunk * 256;     // 0..3071
    const float* src; int off;
    if (idx < 1024)       { src = q; off = idx; }
    else if (idx < 2048)  { src = k; off = idx - 1024; }
    else                  { src = v; off = idx - 2048; }
    float4 g0 = *(const float4*)(src + (size_t)bsr0 * Hx + off);
    float4 g1 = *(const float4*)(src + (size_t)bsr1 * Hx + off);
#pragma unroll
    for (int h = 0; h < 4; ++h) {
      float4 wiv = *(const float4*)(wi + h * 3 * Hx + idx);
      float4 wfv = *(const float4*)(wf + h * 3 * Hx + idx);
      p[0][h]     += g0.x*wiv.x + g0.y*wiv.y + g0.z*wiv.z + g0.w*wiv.w;
      p[1][h]     += g1.x*wiv.x + g1.y*wiv.y + g1.z*wiv.z + g1.w*wiv.w;
      p[0][4 + h] += g0.x*wfv.x + g0.y*wfv.y + g0.z*wfv.z + g0.w*wfv.w;
      p[1][4 + h] += g1.x*wfv.x + g1.y*wfv.y + g1.z*wfv.z + g1.w*wfv.w;
    }
    if (idx < 2048) {
      unsigned short* dst = (idx < 1024) ? Qb : Kb;
      const int hh = off >> 8, d = off & 255;
      const int b0 = bsr0 >> 11, s0p = bsr0 & 2047;
      const int b1 = bsr1 >> 11, s1p = bsr1 & 2047;
      ushort4 o0; o0.x=f2bf(g0.x); o0.y=f2bf(g0.y); o0.z=f2bf(g0.z); o0.w=f2bf(g0.w);
      ushort4 o1; o1.x=f2bf(g1.x); o1.y=f2bf(g1.y); o1.z=f2bf(g1.z); o1.w=f2bf(g1.w);
      *(ushort4*)(dst + ((size_t)(b0 * NHx + hh) * Sx + s0p) * DHx + d) = o0;
      *(ushort4*)(dst + ((size_t)(b1 * NHx + hh) * Sx + s1p) * DHx + d) = o1;
    }
  }
#pragma unroll
  for (int rr = 0; rr < 2; ++rr)
#pragma unroll
    for (int g2 = 0; g2 < 8; ++g2) {
      float x = p[rr][g2];
      x += __shfl_xor(x, 1);  x += __shfl_xor(x, 2);  x += __shfl_xor(x, 4);
      x += __shfl_xor(x, 8);  x += __shfl_xor(x, 16); x += __shfl_xor(x, 32);
      p[rr][g2] = x;
    }
  if (l == 0) {
#pragma unroll
    for (int rr = 0; rr < 2; ++rr) {
      const int bs = bs0 + w * 2 + rr;
      const int b = bs >> 11, spos = bs & 2047;
#pragma unroll
      for (int h = 0; h < 4; ++h) {
        ig[(size_t)(b * NHx + h) * Sx + spos] = p[rr][h] + bi[h];
        fg[(size_t)(b * NHx + h) * Sx + spos] = p[rr][4 + h] + bf[h];
      }
    }
  }
}

// ---------- K2: per-(b,h) scan: a[], M[], exp(-m)[] -------------------------
__global__ __launch_bounds__(256)
void scan_kernel(const float* __restrict__ ig, const float* __restrict__ fg,
                 float* __restrict__ av, float* __restrict__ Mv,
                 float* __restrict__ nfv)
{
  const int bh = blockIdx.x;
  const int t  = threadIdx.x;
  const size_t base = (size_t)bh * Sx;
  const int s0 = t * 8;
  float4 f0 = *(const float4*)(fg + base + s0);
  float4 f1 = *(const float4*)(fg + base + s0 + 4);
  float4 g0 = *(const float4*)(ig + base + s0);
  float4 g1 = *(const float4*)(ig + base + s0 + 4);
  float xf[8] = {f0.x,f0.y,f0.z,f0.w,f1.x,f1.y,f1.z,f1.w};
  float xi[8] = {g0.x,g0.y,g0.z,g0.w,g1.x,g1.y,g1.z,g1.w};
  float ps[8];
  float run = 0.0f;
#pragma unroll
  for (int i = 0; i < 8; ++i) { run += logsigf(xf[i]); ps[i] = run; }
  __shared__ float ssum[256];
  __shared__ float smax[256];
  ssum[t] = run;
  __syncthreads();
  for (int st = 1; st < 256; st <<= 1) {
    float addv = (t >= st) ? ssum[t - st] : 0.0f;
    __syncthreads();
    ssum[t] += addv;
    __syncthreads();
  }
  const float exs = (t > 0) ? ssum[t - 1] : 0.0f;
  float a[8], pm[8];
  float rm = -INFINITY;
#pragma unroll
  for (int i = 0; i < 8; ++i) {
    a[i] = xi[i] - (exs + ps[i]);
    rm = fmaxf(rm, a[i]);
    pm[i] = rm;
  }
  smax[t] = rm;
  __syncthreads();
  for (int st = 1; st < 256; st <<= 1) {
    float mv = (t >= st) ? smax[t - st] : -INFINITY;
    __syncthreads();
    smax[t] = fmaxf(smax[t], mv);
    __syncthreads();
  }
  const float exm = (t > 0) ? smax[t - 1] : -INFINITY;
#pragma unroll
  for (int i = 0; i < 8; ++i) {
    const float M = fmaxf(exm, pm[i]);
    const float F = exs + ps[i];
    av[base + s0 + i]  = a[i];
    Mv[base + s0 + i]  = M;
    nfv[base + s0 + i] = expf(-(F + M));
  }
}

// ---------- K3: V -> bf16 transposed global Vt[bh][d][s] --------------------
__global__ __launch_bounds__(256)
void vtrans_kernel(const float* __restrict__ v, unsigned short* __restrict__ vt)
{
  __shared__ float tile[64][68];
  const int st0 = blockIdx.x * 64, dt0 = blockIdx.y * 64;
  const int bh = blockIdx.z, b = bh >> 2, h = bh & 3;
  const int t = threadIdx.x;
#pragma unroll
  for (int i = 0; i < 4; ++i) {
    int u = t + 256 * i;
    int r = u >> 4, c4 = (u & 15) * 4;
    const float* p = v + ((size_t)(b * Sx) + st0 + r) * Hx + h * DHx + dt0 + c4;
    float4 vv = *(const float4*)p;
    tile[r][c4] = vv.x; tile[r][c4+1] = vv.y; tile[r][c4+2] = vv.z; tile[r][c4+3] = vv.w;
  }
  __syncthreads();
#pragma unroll
  for (int i = 0; i < 4; ++i) {
    int u = t + 256 * i;
    int dr = u >> 4, c4 = (u & 15) * 4;
    ushort4 o;
    o.x = f2bf(tile[c4+0][dr]); o.y = f2bf(tile[c4+1][dr]);
    o.z = f2bf(tile[c4+2][dr]); o.w = f2bf(tile[c4+3][dr]);
    *(ushort4*)(vt + ((size_t)bh * DHx + dt0 + dr) * Sx + st0 + c4) = o;
  }
}

// ---------- K4a: pass1 — LDS-pipelined flash mLSTM ---------------------------
// 256 thr = 4 waves. Unit = (bh, q-tile of 64 rows, key chunk). Wave owns 16
// q-rows, does swapped-QK + full-D PV; P wave-local (shfl repack). K/V staged
// global->reg->LDS, double buffered, ONE barrier/iter. K XOR-swizzled rows,
// V 80B-pitch rows (both ~2-way banks). ti>=16 split in 2 chunks -> partials.
__global__ __launch_bounds__(256, 2)
void mlstm_pass1(const unsigned short* __restrict__ Qb,
                 const unsigned short* __restrict__ Kb,
                 const unsigned short* __restrict__ Vt,
                 const float* __restrict__ av, const float* __restrict__ Mv,
                 const float* __restrict__ nfv, const float* __restrict__ lnw,
                 float* __restrict__ part, float* __restrict__ out)
{
  __shared__ __align__(16) unsigned char Kls[2][16384];  // 32 keys x 512B
  __shared__ __align__(16) unsigned char Vls[2][20480];  // 256 d x 80B

  const int bh = blockIdx.x, b = bh >> 2, h = bh & 3;
  const int u = blockIdx.y;
  int ti, c, nchunks;
  if (u < 32) { ti = 31 - (u >> 1); c = u & 1; nchunks = 2; }
  else        { ti = 47 - u;        c = 0;     nchunks = 1; }
  const int i0 = ti * 64;
  const int tjs = (nchunks == 2) ? c * (ti + 1) : 0;
  const int tje = (nchunks == 2) ? (c + 1) * (ti + 1) : (2 * ti + 2);

  const int tid = threadIdx.x;
  const int w = tid >> 6, l = tid & 63;
  const int lg = l >> 4, ll = l & 15;
  const size_t bhS = (size_t)bh * Sx;
  const int qrow = i0 + w * 16 + ll;

  // Q B-frags for this wave's 16 q-rows
  bf16x8 qf[8];
  {
    const unsigned short* qp = Qb + (bhS + qrow) * DHx + lg * 8;
#pragma unroll
    for (int d8 = 0; d8 < 8; ++d8) qf[d8] = *(const bf16x8*)(qp + d8 * 32);
  }
  const float Mq = Mv[bhS + qrow];

  f32x4 acc[16];
#pragma unroll
  for (int jt = 0; jt < 16; ++jt) acc[jt] = f32x4{0, 0, 0, 0};
  float rsum = 0.f;

  const unsigned short* kgb = Kb + bhS * (size_t)DHx;
  const unsigned short* vgb = Vt + (size_t)bh * DHx * Sx;

  uint4 rK[4], rV[4];
  auto sload = [&](int tj) {
    const int j0 = tj * 32;
#pragma unroll
    for (int r = 0; r < 4; ++r) {
      const int idx = tid + 256 * r;
      rK[r] = *(const uint4*)(kgb + (size_t)(j0 + (idx >> 5)) * DHx + (idx & 31) * 8);
    }
#pragma unroll
    for (int r = 0; r < 4; ++r) {
      const int idx = tid + 256 * r;
      rV[r] = *(const uint4*)(vgb + (size_t)(idx >> 2) * Sx + j0 + (idx & 3) * 8);
    }
  };
  auto swrite = [&](int bsel) {
    char* KB = (char*)Kls[bsel];
    char* VB = (char*)Vls[bsel];
#pragma unroll
    for (int r = 0; r < 4; ++r) {
      const int idx = tid + 256 * r;
      const int key = idx >> 5, ch = idx & 31;
      *(uint4*)(KB + key * 512 + ((ch ^ (key & 7)) << 4)) = rK[r];
    }
#pragma unroll
    for (int r = 0; r < 4; ++r) {
      const int idx = tid + 256 * r;
      *(uint4*)(VB + (idx >> 2) * 80 + (idx & 3) * 16) = rV[r];
    }
  };

  sload(tjs);
  swrite(0);
  if (tjs + 1 < tje) sload(tjs + 1);
  __syncthreads();

  int cur = 0;
  for (int tj = tjs; tj < tje; ++tj, cur ^= 1) {
    if (tj + 1 < tje) swrite(cur ^ 1);     // stage tile tj+1 (regs -> LDS)
    if (tj + 2 < tje) sload(tj + 2);       // issue loads for tj+2 (overlap)
    const int j0 = tj * 32;
    const char* KB = (const char*)Kls[cur];
    const char* VB = (const char*)Vls[cur];

    // ---- QK: two 16-key subtiles from swizzled LDS ----
    f32x4 st0 = {0,0,0,0}, st1 = {0,0,0,0};
#pragma unroll
    for (int d8 = 0; d8 < 8; ++d8) {
      const int co = (((d8 << 2) | lg) ^ (ll & 7)) << 4;
      bf16x8 kf0 = *(const bf16x8*)(KB + ll * 512 + co);
      bf16x8 kf1 = *(const bf16x8*)(KB + 8192 + ll * 512 + co);
      st0 = __builtin_amdgcn_mfma_f32_16x16x32_bf16(kf0, qf[d8], st0, 0, 0, 0);
      st1 = __builtin_amdgcn_mfma_f32_16x16x32_bf16(kf1, qf[d8], st1, 0, 0, 0);
    }
    const f32x4 a4_0 = *(const f32x4*)(av + bhS + j0 + lg * 4);
    const f32x4 a4_1 = *(const f32x4*)(av + bhS + j0 + 16 + lg * 4);

    // ---- transform: mask + decay + rsum; pack bf16; lane redistribution ----
    unsigned x0[4], x1[4];
#pragma unroll
    for (int kt = 0; kt < 2; ++kt) {
      const f32x4 s = kt ? st1 : st0;
      const f32x4 a = kt ? a4_1 : a4_0;
      const int kb = j0 + kt * 16 + 4 * lg;
      float p0 = (kb + 0 <= qrow) ? s[0] * (RSQ * __expf(a[0] - Mq)) : 0.f;
      float p1 = (kb + 1 <= qrow) ? s[1] * (RSQ * __expf(a[1] - Mq)) : 0.f;
      float p2 = (kb + 2 <= qrow) ? s[2] * (RSQ * __expf(a[2] - Mq)) : 0.f;
      float p3 = (kb + 3 <= qrow) ? s[3] * (RSQ * __expf(a[3] - Mq)) : 0.f;
      rsum += (p0 + p1) + (p2 + p3);
      unsigned lo = pk2bf(p0, p1), hi = pk2bf(p2, p3);
      unsigned plo = __shfl_xor(lo, 16), phi = __shfl_xor(hi, 16);
      bool ge = ((lg & 1) == 0);
      unsigned* x = kt ? x1 : x0;
      x[0] = ge ? lo : plo;  x[1] = ge ? hi : phi;
      x[2] = ge ? plo : lo;  x[3] = ge ? phi : hi;
    }
    unsigned pw0, pw1, pw2, pw3;
#pragma unroll
    for (int j = 0; j < 4; ++j) {
      unsigned yA = __shfl_xor(x0[j], 32);
      unsigned yB = __shfl_xor(x1[j], 32);
      unsigned r = (lg == 0) ? x0[j] : (lg == 1) ? yA : (lg == 2) ? yB : x1[j];
      if (j == 0) pw0 = r; else if (j == 1) pw1 = r; else if (j == 2) pw2 = r; else pw3 = r;
    }
    u32x4 w4 = {pw0, pw1, pw2, pw3};
    bf16x8 pb = __builtin_bit_cast(bf16x8, w4);

    // ---- PV: 16 d-subtiles from padded LDS ----
#pragma unroll
    for (int ds2 = 0; ds2 < 16; ++ds2) {
      bf16x8 vf = *(const bf16x8*)(VB + (ds2 * 16 + ll) * 80 + lg * 16);
      acc[ds2] = __builtin_amdgcn_mfma_f32_16x16x32_bf16(vf, pb, acc[ds2], 0, 0, 0);
    }
    __syncthreads();
  }

  // ---- epilogue ----
  float rs = rsum;
  rs += __shfl_xor(rs, 16); rs += __shfl_xor(rs, 32);
  if (nchunks == 1) {
    float s1 = 0.f, s2 = 0.f;
#pragma unroll
    for (int jt = 0; jt < 16; ++jt)
#pragma unroll
      for (int r = 0; r < 4; ++r) {
        const float x = acc[jt][r];
        s1 += x; s2 += x * x;
      }
    s1 += __shfl_xor(s1, 16); s1 += __shfl_xor(s1, 32);
    s2 += __shfl_xor(s2, 16); s2 += __shfl_xor(s2, 32);
    const float nf = nfv[bhS + qrow];
    const float inv = 1.f / (fmaxf(fabsf(rs), nf) + 1e-6f);
    const float mean = s1 * inv * (1.f / 256.f);
    const float ex2  = s2 * inv * inv * (1.f / 256.f);
    const float var  = ex2 - mean * mean;
    const float rstd = rsqrtf(var + 1e-5f);
    float* op = out + ((size_t)b * Sx + qrow) * Hx + h * DHx;
#pragma unroll
    for (int jt = 0; jt < 16; ++jt) {
      const int dbase = jt * 16 + lg * 4;
      f32x4 lw = *(const f32x4*)(lnw + h * DHx + dbase);
      float4 o;
      o.x = (acc[jt][0] * inv - mean) * rstd * (1.f + lw[0]);
      o.y = (acc[jt][1] * inv - mean) * rstd * (1.f + lw[1]);
      o.z = (acc[jt][2] * inv - mean) * rstd * (1.f + lw[2]);
      o.w = (acc[jt][3] * inv - mean) * rstd * (1.f + lw[3]);
      *(float4*)(op + dbase) = o;
    }
  } else {
    const int pidx = (bh * 16 + (ti - 16)) * 2 + c;
    float* pO = part + (size_t)pidx * 16448;
    float* pq = pO + (w * 16 + ll) * 256;
#pragma unroll
    for (int jt = 0; jt < 16; ++jt)
      *(f32x4*)(pq + jt * 16 + lg * 4) = acc[jt];
    if (lg == 0) pO[16384 + w * 16 + ll] = rs;
  }
}

// ---------- K4b: pass2 — combine 2 chunks + normalizer + group-LN -----------
__global__ __launch_bounds__(256)
void mlstm_pass2(const float* __restrict__ part, const float* __restrict__ nfv,
                 const float* __restrict__ lnw, float* __restrict__ out)
{
  const int bh = blockIdx.x, b = bh >> 2, h = bh & 3;
  const int ti = 16 + (int)blockIdx.y;
  const int t = threadIdx.x;
  const int q = t >> 2, ds0 = (t & 3) * 64;
  const size_t bhS = (size_t)bh * Sx;
  const int qrow = ti * 64 + q;
  const float* p0 = part + (size_t)((bh * 16 + (ti - 16)) * 2) * 16448;
  const float* p1 = p0 + 16448;

  f32x4 o[16];
  const float* pq0 = p0 + q * 256 + ds0;
  const float* pq1 = p1 + q * 256 + ds0;
#pragma unroll
  for (int j = 0; j < 16; ++j)
    o[j] = *(const f32x4*)(pq0 + j * 4) + *(const f32x4*)(pq1 + j * 4);
  const float rs = p0[16384 + q] + p1[16384 + q];

  float s1 = 0.f, s2 = 0.f;
#pragma unroll
  for (int j = 0; j < 16; ++j)
#pragma unroll
    for (int r = 0; r < 4; ++r) {
      const float x = o[j][r];
      s1 += x; s2 += x * x;
    }
  s1 += __shfl_xor(s1, 1); s1 += __shfl_xor(s1, 2);
  s2 += __shfl_xor(s2, 1); s2 += __shfl_xor(s2, 2);

  const float nf = nfv[bhS + qrow];
  const float inv = 1.f / (fmaxf(fabsf(rs), nf) + 1e-6f);
  const float mean = s1 * inv * (1.f / 256.f);
  const float ex2  = s2 * inv * inv * (1.f / 256.f);
  const float var  = ex2 - mean * mean;
  const float rstd = rsqrtf(var + 1e-5f);
  float* op = out + ((size_t)b * Sx + qrow) * Hx + h * DHx + ds0;
#pragma unroll
  for (int j = 0; j < 16; ++j) {
    f32x4 lw = *(const f32x4*)(lnw + h * DHx + ds0 + j * 4);
    float4 ov;
    ov.x = (o[j][0] * inv - mean) * rstd * (1.f + lw[0]);
    ov.y = (o[j][1] * inv - mean) * rstd * (1.f + lw[1]);
    ov.z = (o[j][2] * inv - mean) * rstd * (1.f + lw[2]);
    ov.w = (o[j][3] * inv - mean) * rstd * (1.f + lw[3]);
    *(float4*)(op + j * 4) = ov;
  }
}

extern "C" void kernel_launch(void* const* d_in, const int* in_sizes, int n_in,
                              void* d_out, int out_size, void* d_ws, size_t ws_size,
                              hipStream_t stream) {
  const float* q   = (const float*)d_in[0];
  const float* k   = (const float*)d_in[1];
  const float* v   = (const float*)d_in[2];
  const float* wi  = (const float*)d_in[3];
  const float* bi  = (const float*)d_in[4];
  const float* wf  = (const float*)d_in[5];
  const float* bf  = (const float*)d_in[6];
  const float* lnw = (const float*)d_in[7];
  float* out = (float*)d_out;
  float* ws  = (float*)d_ws;

  const int G = Bx * NHx * Sx;         // 16384
  float* ig  = ws;
  float* fg  = ws + (size_t)G;
  float* av  = ws + (size_t)2 * G;
  float* Mv  = ws + (size_t)3 * G;
  float* nfv = ws + (size_t)4 * G;
  unsigned short* Qb = (unsigned short*)(ws + (size_t)5 * G);
  unsigned short* Kb = Qb + (size_t)Bx * Sx * Hx;   // 4,194,304 elems
  unsigned short* Vt = Kb + (size_t)Bx * Sx * Hx;
  float* part = (float*)(Vt + (size_t)Bx * Sx * Hx); // 256 x 16448 f32 = 16.8 MB
  // total ws use: ~41.5 MB

  gates_kernel<<<Bx * Sx / 16, 512, 0, stream>>>(q, k, v, wi, bi, wf, bf, ig, fg, Qb, Kb);
  scan_kernel<<<Bx * NHx, 256, 0, stream>>>(ig, fg, av, Mv, nfv);
  dim3 gT(Sx / 64, DHx / 64, Bx * NHx);
  vtrans_kernel<<<gT, 256, 0, stream>>>(v, Vt);
  dim3 g1(Bx * NHx, 48);               // x = bh (XCD), y = unit (LPT order)
  mlstm_pass1<<<g1, 256, 0, stream>>>(Qb, Kb, Vt, av, Mv, nfv, lnw, part, out);
  dim3 g2(Bx * NHx, 16);
  mlstm_pass2<<<g2, 256, 0, stream>>>(part, nfv, lnw, out);
}

// Round 11
// 126.787 us; speedup vs baseline: 1.7508x; 1.6633x over previous
//
#include <hip/hip_runtime.h>
#include <hip/hip_bf16.h>
#include <cstddef>

// Dims fixed by reference: B=2, S=2048, H=1024, NH=4, DH=256
constexpr int Bx = 2, Sx = 2048, Hx = 1024, NHx = 4, DHx = 256;
constexpr float RSQ = 0.0625f;   // 1/sqrt(256)

typedef __attribute__((ext_vector_type(8))) short    bf16x8;
typedef __attribute__((ext_vector_type(4))) float    f32x4;

__device__ __forceinline__ float logsigf(float x) {
  return (x >= 0.0f) ? -log1pf(expf(-x)) : x - log1pf(expf(x));
}
__device__ __forceinline__ unsigned short f2bf(float x) {  // RNE f32->bf16
  unsigned u = __builtin_bit_cast(unsigned, x);
  u = (u + 0x7fffu + ((u >> 16) & 1u)) >> 16;
  return (unsigned short)u;
}
__device__ __forceinline__ unsigned pk2bf(float a, float b) {
  return (unsigned)f2bf(a) | ((unsigned)f2bf(b) << 16);
}

// ---------- K1: gates (ig/fg) + bf16 side-copies of Q,K ---------------------
// 16 rows per block (512 thr = 8 waves, 2 rows/wave) to amortize W reads.
__global__ __launch_bounds__(512)
void gates_kernel(const float* __restrict__ q, const float* __restrict__ k,
                  const float* __restrict__ v,
                  const float* __restrict__ wi, const float* __restrict__ bi,
                  const float* __restrict__ wf, const float* __restrict__ bf,
                  float* __restrict__ ig, float* __restrict__ fg,
                  unsigned short* __restrict__ Qb, unsigned short* __restrict__ Kb)
{
  const int w = threadIdx.x >> 6, l = threadIdx.x & 63;
  const int bs0 = blockIdx.x * 16;
  const int bsr0 = bs0 + w * 2, bsr1 = bsr0 + 1;
  float p[2][8];
#pragma unroll
  for (int rr = 0; rr < 2; ++rr)
#pragma unroll
    for (int g2 = 0; g2 < 8; ++g2) p[rr][g2] = 0.f;

#pragma unroll
  for (int chunk = 0; chunk < 12; ++chunk) {
    const int idx = l * 4 + chunk * 256;     // 0..3071
    const float* src; int off;
    if (idx < 1024)       { src = q; off = idx; }
    else if (idx < 2048)  { src = k; off = idx - 1024; }
    else                  { src = v; off = idx - 2048; }
    float4 g0 = *(const float4*)(src + (size_t)bsr0 * Hx + off);
    float4 g1 = *(const float4*)(src + (size_t)bsr1 * Hx + off);
#pragma unroll
    for (int h = 0; h < 4; ++h) {
      float4 wiv = *(const float4*)(wi + h * 3 * Hx + idx);
      float4 wfv = *(const float4*)(wf + h * 3 * Hx + idx);
      p[0][h]     += g0.x*wiv.x + g0.y*wiv.y + g0.z*wiv.z + g0.w*wiv.w;
      p[1][h]     += g1.x*wiv.x + g1.y*wiv.y + g1.z*wiv.z + g1.w*wiv.w;
      p[0][4 + h] += g0.x*wfv.x + g0.y*wfv.y + g0.z*wfv.z + g0.w*wfv.w;
      p[1][4 + h] += g1.x*wfv.x + g1.y*wfv.y + g1.z*wfv.z + g1.w*wfv.w;
    }
    if (idx < 2048) {
      unsigned short* dst = (idx < 1024) ? Qb : Kb;
      const int hh = off >> 8, d = off & 255;
      const int b0 = bsr0 >> 11, s0p = bsr0 & 2047;
      const int b1 = bsr1 >> 11, s1p = bsr1 & 2047;
      ushort4 o0; o0.x=f2bf(g0.x); o0.y=f2bf(g0.y); o0.z=f2bf(g0.z); o0.w=f2bf(g0.w);
      ushort4 o1; o1.x=f2bf(g1.x); o1.y=f2bf(g1.y); o1.z=f2bf(g1.z); o1.w=f2bf(g1.w);
      *(ushort4*)(dst + ((size_t)(b0 * NHx + hh) * Sx + s0p) * DHx + d) = o0;
      *(ushort4*)(dst + ((size_t)(b1 * NHx + hh) * Sx + s1p) * DHx + d) = o1;
    }
  }
#pragma unroll
  for (int rr = 0; rr < 2; ++rr)
#pragma unroll
    for (int g2 = 0; g2 < 8; ++g2) {
      float x = p[rr][g2];
      x += __shfl_xor(x, 1);  x += __shfl_xor(x, 2);  x += __shfl_xor(x, 4);
      x += __shfl_xor(x, 8);  x += __shfl_xor(x, 16); x += __shfl_xor(x, 32);
      p[rr][g2] = x;
    }
  if (l == 0) {
#pragma unroll
    for (int rr = 0; rr < 2; ++rr) {
      const int bs = bs0 + w * 2 + rr;
      const int b = bs >> 11, spos = bs & 2047;
#pragma unroll
      for (int h = 0; h < 4; ++h) {
        ig[(size_t)(b * NHx + h) * Sx + spos] = p[rr][h] + bi[h];
        fg[(size_t)(b * NHx + h) * Sx + spos] = p[rr][4 + h] + bf[h];
      }
    }
  }
}

// ---------- K2: per-(b,h) scan: a[], M[], exp(-m)[] -------------------------
__global__ __launch_bounds__(256)
void scan_kernel(const float* __restrict__ ig, const float* __restrict__ fg,
                 float* __restrict__ av, float* __restrict__ Mv,
                 float* __restrict__ nfv)
{
  const int bh = blockIdx.x;
  const int t  = threadIdx.x;
  const size_t base = (size_t)bh * Sx;
  const int s0 = t * 8;
  float4 f0 = *(const float4*)(fg + base + s0);
  float4 f1 = *(const float4*)(fg + base + s0 + 4);
  float4 g0 = *(const float4*)(ig + base + s0);
  float4 g1 = *(const float4*)(ig + base + s0 + 4);
  float xf[8] = {f0.x,f0.y,f0.z,f0.w,f1.x,f1.y,f1.z,f1.w};
  float xi[8] = {g0.x,g0.y,g0.z,g0.w,g1.x,g1.y,g1.z,g1.w};
  float ps[8];
  float run = 0.0f;
#pragma unroll
  for (int i = 0; i < 8; ++i) { run += logsigf(xf[i]); ps[i] = run; }
  __shared__ float ssum[256];
  __shared__ float smax[256];
  ssum[t] = run;
  __syncthreads();
  for (int st = 1; st < 256; st <<= 1) {
    float addv = (t >= st) ? ssum[t - st] : 0.0f;
    __syncthreads();
    ssum[t] += addv;
    __syncthreads();
  }
  const float exs = (t > 0) ? ssum[t - 1] : 0.0f;
  float a[8], pm[8];
  float rm = -INFINITY;
#pragma unroll
  for (int i = 0; i < 8; ++i) {
    a[i] = xi[i] - (exs + ps[i]);
    rm = fmaxf(rm, a[i]);
    pm[i] = rm;
  }
  smax[t] = rm;
  __syncthreads();
  for (int st = 1; st < 256; st <<= 1) {
    float mv = (t >= st) ? smax[t - st] : -INFINITY;
    __syncthreads();
    smax[t] = fmaxf(smax[t], mv);
    __syncthreads();
  }
  const float exm = (t > 0) ? smax[t - 1] : -INFINITY;
#pragma unroll
  for (int i = 0; i < 8; ++i) {
    const float M = fmaxf(exm, pm[i]);
    const float F = exs + ps[i];
    av[base + s0 + i]  = a[i];
    Mv[base + s0 + i]  = M;
    nfv[base + s0 + i] = expf(-(F + M));
  }
}

// ---------- K3: V -> bf16 transposed global Vt[bh][d][s] --------------------
__global__ __launch_bounds__(256)
void vtrans_kernel(const float* __restrict__ v, unsigned short* __restrict__ vt)
{
  __shared__ float tile[64][68];
  const int st0 = blockIdx.x * 64, dt0 = blockIdx.y * 64;
  const int bh = blockIdx.z, b = bh >> 2, h = bh & 3;
  const int t = threadIdx.x;
#pragma unroll
  for (int i = 0; i < 4; ++i) {
    int u = t + 256 * i;
    int r = u >> 4, c4 = (u & 15) * 4;
    const float* p = v + ((size_t)(b * Sx) + st0 + r) * Hx + h * DHx + dt0 + c4;
    float4 vv = *(const float4*)p;
    tile[r][c4] = vv.x; tile[r][c4+1] = vv.y; tile[r][c4+2] = vv.z; tile[r][c4+3] = vv.w;
  }
  __syncthreads();
#pragma unroll
  for (int i = 0; i < 4; ++i) {
    int u = t + 256 * i;
    int dr = u >> 4, c4 = (u & 15) * 4;
    ushort4 o;
    o.x = f2bf(tile[c4+0][dr]); o.y = f2bf(tile[c4+1][dr]);
    o.z = f2bf(tile[c4+2][dr]); o.w = f2bf(tile[c4+3][dr]);
    *(ushort4*)(vt + ((size_t)bh * DHx + dt0 + dr) * Sx + st0 + c4) = o;
  }
}

// ---------- K4: flash mLSTM on MFMA (R5 base + T2 XOR swizzle) ---------------
// 512 thr = 8 waves. BQ=32 q-rows per block, BK=128 keys per iter.
// QK: wave w: keys [w*16, w*16+16) x 32 q; Q frags from LDS, K frags from L2.
// PV: wave w: d-slice [w*32, w*32+32) x 32 q; V frags from L2, P from LDS.
// One barrier/iter, P double-buffered. Qls/Pls XOR-swizzled (chunk ^= row&7,
// 16B granularity, same involution on write and read) -> conflict-free reads.
__global__ __launch_bounds__(512, 4)
void mlstm_mfma(const unsigned short* __restrict__ Qb,
                const unsigned short* __restrict__ Kb,
                const unsigned short* __restrict__ Vt,
                const float* __restrict__ av, const float* __restrict__ Mv,
                const float* __restrict__ nfv, const float* __restrict__ lnw,
                float* __restrict__ out)
{
  __shared__ __align__(16) unsigned short Qls[32 * 256];      // 16 KB
  __shared__ __align__(16) unsigned short Pls[2][32 * 128];   // 16 KB
  __shared__ float red[8][2][16][3];                          // 3 KB

  const int bh = blockIdx.x, b = bh >> 2, h = bh & 3;
  const int ti = (int)gridDim.y - 1 - (int)blockIdx.y;   // big tiles first
  const int i0 = ti * 32;
  const int tid = threadIdx.x;
  const int w = tid >> 6, l = tid & 63;
  const int lg = l >> 4, ll = l & 15;
  const size_t bhS = (size_t)bh * Sx;

  // stage Q tile (32 x 256) into LDS once, XOR-swizzled
  {
    const int r = tid >> 4, ch0 = (tid & 15) * 2;
    const unsigned short* qp = Qb + (bhS + i0 + r) * DHx + ch0 * 8;
    *(bf16x8*)&Qls[r * 256 + ((ch0 ^ (r & 7)) << 3)]       = *(const bf16x8*)qp;
    *(bf16x8*)&Qls[r * 256 + (((ch0 + 1) ^ (r & 7)) << 3)] = *(const bf16x8*)(qp + 8);
  }
  float Mq[2], nfq[2];
#pragma unroll
  for (int qg = 0; qg < 2; ++qg) {
    Mq[qg]  = Mv[bhS + i0 + qg * 16 + ll];
    nfq[qg] = nfv[bhS + i0 + qg * 16 + ll];
  }
  f32x4 acc[2][2];   // [dt][qg]: d = w*32+dt*16+lg*4+r, q = qg*16+ll
#pragma unroll
  for (int dt = 0; dt < 2; ++dt)
#pragma unroll
    for (int qg = 0; qg < 2; ++qg) acc[dt][qg] = f32x4{0, 0, 0, 0};
  float rsum[2] = {0.f, 0.f};
  __syncthreads();

  const int nt = (i0 + 32 + 127) >> 7;
  for (int tj = 0; tj < nt; ++tj) {
    const int j0 = tj << 7;
    const int kb = j0 + w * 16;
    // ---- K frags from L2 ----
    bf16x8 kf[8];
    {
      const unsigned short* kp = Kb + (bhS + kb + ll) * DHx + lg * 8;
#pragma unroll
      for (int d8 = 0; d8 < 8; ++d8) kf[d8] = *(const bf16x8*)(kp + d8 * 32);
    }
    const f32x4 a4 = *(const f32x4*)(av + bhS + kb + lg * 4);
    // ---- QK: Q frags from swizzled LDS, 16 MFMA ----
    f32x4 st0 = {0,0,0,0}, st1 = {0,0,0,0};
#pragma unroll
    for (int d8 = 0; d8 < 8; ++d8) {
      const int ph = ((4 * d8 + lg) ^ (ll & 7)) << 3;
      bf16x8 q0 = *(const bf16x8*)&Qls[ll * 256 + ph];
      bf16x8 q1 = *(const bf16x8*)&Qls[(16 + ll) * 256 + ph];
      st0 = __builtin_amdgcn_mfma_f32_16x16x32_bf16(kf[d8], q0, st0, 0, 0, 0);
      st1 = __builtin_amdgcn_mfma_f32_16x16x32_bf16(kf[d8], q1, st1, 0, 0, 0);
    }
    // ---- transform + P write (swizzled) ----
#pragma unroll
    for (int qg = 0; qg < 2; ++qg) {
      const f32x4 s = qg ? st1 : st0;
      const int qrow = i0 + qg * 16 + ll;
      const int k0i = kb + lg * 4;
      float p0 = (k0i + 0 <= qrow) ? s[0] * (RSQ * __expf(a4[0] - Mq[qg])) : 0.f;
      float p1 = (k0i + 1 <= qrow) ? s[1] * (RSQ * __expf(a4[1] - Mq[qg])) : 0.f;
      float p2 = (k0i + 2 <= qrow) ? s[2] * (RSQ * __expf(a4[2] - Mq[qg])) : 0.f;
      float p3 = (k0i + 3 <= qrow) ? s[3] * (RSQ * __expf(a4[3] - Mq[qg])) : 0.f;
      rsum[qg] += (p0 + p1) + (p2 + p3);
      uint2 pk = make_uint2(pk2bf(p0, p1), pk2bf(p2, p3));
      const int pc = (((2 * w + (lg >> 1)) ^ (ll & 7)) << 3) + ((lg & 1) << 2);
      *(uint2*)&Pls[tj & 1][(qg * 16 + ll) * 128 + pc] = pk;
    }
    __syncthreads();
    // ---- PV: V frags from L2, P frags from swizzled LDS, 16 MFMA ----
    const unsigned short* vp = Vt + ((size_t)bh * DHx + w * 32 + ll) * Sx + j0 + lg * 8;
#pragma unroll
    for (int kap = 0; kap < 4; ++kap) {
      const int pc = ((4 * kap + lg) ^ (ll & 7)) << 3;
      bf16x8 pf0 = *(const bf16x8*)&Pls[tj & 1][ll * 128 + pc];
      bf16x8 pf1 = *(const bf16x8*)&Pls[tj & 1][(16 + ll) * 128 + pc];
#pragma unroll
      for (int dt = 0; dt < 2; ++dt) {
        bf16x8 vf = *(const bf16x8*)(vp + (size_t)dt * 16 * Sx + kap * 32);
        acc[dt][0] = __builtin_amdgcn_mfma_f32_16x16x32_bf16(vf, pf0, acc[dt][0], 0, 0, 0);
        acc[dt][1] = __builtin_amdgcn_mfma_f32_16x16x32_bf16(vf, pf1, acc[dt][1], 0, 0, 0);
      }
    }
  }

  // ---- cross-wave reductions: rsum (QK role), s1/s2 (PV role) ----
#pragma unroll
  for (int qg = 0; qg < 2; ++qg) {
    float rs = rsum[qg];
    float s1 = 0.f, s2 = 0.f;
#pragma unroll
    for (int dt = 0; dt < 2; ++dt)
#pragma unroll
      for (int r = 0; r < 4; ++r) {
        const float x = acc[dt][qg][r];
        s1 += x; s2 += x * x;
      }
    rs += __shfl_xor(rs, 16); rs += __shfl_xor(rs, 32);
    s1 += __shfl_xor(s1, 16); s1 += __shfl_xor(s1, 32);
    s2 += __shfl_xor(s2, 16); s2 += __shfl_xor(s2, 32);
    if (l < 16) {
      red[w][qg][l][0] = rs;
      red[w][qg][l][1] = s1;
      red[w][qg][l][2] = s2;
    }
  }
  __syncthreads();

  // ---- epilogue: normalizer + group-LN, direct from accumulators ----
#pragma unroll
  for (int qg = 0; qg < 2; ++qg) {
    const int q = qg * 16 + ll;
    float rs = 0.f, s1 = 0.f, s2 = 0.f;
#pragma unroll
    for (int wj = 0; wj < 8; ++wj) {
      rs += red[wj][qg][ll][0];
      s1 += red[wj][qg][ll][1];
      s2 += red[wj][qg][ll][2];
    }
    const float inv = 1.f / (fmaxf(fabsf(rs), nfq[qg]) + 1e-6f);
    const float mean = s1 * inv * (1.f / 256.f);
    const float ex2  = s2 * inv * inv * (1.f / 256.f);
    const float var  = ex2 - mean * mean;
    const float rstd = rsqrtf(var + 1e-5f);
    float* op = out + ((size_t)b * Sx + i0 + q) * Hx + h * DHx;
#pragma unroll
    for (int dt = 0; dt < 2; ++dt) {
      const int dbase = w * 32 + dt * 16 + lg * 4;
      f32x4 lw = *(const f32x4*)(lnw + h * DHx + dbase);
      float4 o;
      o.x = (acc[dt][qg][0] * inv - mean) * rstd * (1.f + lw[0]);
      o.y = (acc[dt][qg][1] * inv - mean) * rstd * (1.f + lw[1]);
      o.z = (acc[dt][qg][2] * inv - mean) * rstd * (1.f + lw[2]);
      o.w = (acc[dt][qg][3] * inv - mean) * rstd * (1.f + lw[3]);
      *(float4*)(op + dbase) = o;
    }
  }
}

extern "C" void kernel_launch(void* const* d_in, const int* in_sizes, int n_in,
                              void* d_out, int out_size, void* d_ws, size_t ws_size,
                              hipStream_t stream) {
  const float* q   = (const float*)d_in[0];
  const float* k   = (const float*)d_in[1];
  const float* v   = (const float*)d_in[2];
  const float* wi  = (const float*)d_in[3];
  const float* bi  = (const float*)d_in[4];
  const float* wf  = (const float*)d_in[5];
  const float* bf  = (const float*)d_in[6];
  const float* lnw = (const float*)d_in[7];
  float* out = (float*)d_out;
  float* ws  = (float*)d_ws;

  const int G = Bx * NHx * Sx;         // 16384
  float* ig  = ws;
  float* fg  = ws + (size_t)G;
  float* av  = ws + (size_t)2 * G;
  float* Mv  = ws + (size_t)3 * G;
  float* nfv = ws + (size_t)4 * G;
  unsigned short* Qb = (unsigned short*)(ws + (size_t)5 * G);
  unsigned short* Kb = Qb + (size_t)Bx * Sx * Hx;   // 4,194,304 elems
  unsigned short* Vt = Kb + (size_t)Bx * Sx * Hx;
  // total ws use: ~24.3 MB

  gates_kernel<<<Bx * Sx / 16, 512, 0, stream>>>(q, k, v, wi, bi, wf, bf, ig, fg, Qb, Kb);
  scan_kernel<<<Bx * NHx, 256, 0, stream>>>(ig, fg, av, Mv, nfv);
  dim3 gT(Sx / 64, DHx / 64, Bx * NHx);
  vtrans_kernel<<<gT, 256, 0, stream>>>(v, Vt);
  dim3 g4(Bx * NHx, Sx / 32);          // x = bh (XCD pinned), y = q-tile
  mlstm_mfma<<<g4, 512, 0, stream>>>(Qb, Kb, Vt, av, Mv, nfv, lnw, out);
}

// Round 12
// 116.040 us; speedup vs baseline: 1.9129x; 1.0926x over previous
//
#include <hip/hip_runtime.h>
#include <hip/hip_bf16.h>
#include <cstddef>

// Dims fixed by reference: B=2, S=2048, H=1024, NH=4, DH=256
constexpr int Bx = 2, Sx = 2048, Hx = 1024, NHx = 4, DHx = 256;
constexpr float RSQ = 0.0625f;   // 1/sqrt(256)

typedef __attribute__((ext_vector_type(8))) short    bf16x8;
typedef __attribute__((ext_vector_type(4))) float    f32x4;
typedef __attribute__((ext_vector_type(4))) unsigned u32x4;

__device__ __forceinline__ float logsigf(float x) {
  return (x >= 0.0f) ? -log1pf(expf(-x)) : x - log1pf(expf(x));
}
__device__ __forceinline__ unsigned short f2bf(float x) {  // RNE f32->bf16
  unsigned u = __builtin_bit_cast(unsigned, x);
  u = (u + 0x7fffu + ((u >> 16) & 1u)) >> 16;
  return (unsigned short)u;
}
__device__ __forceinline__ float bf2f(unsigned short u) {
  unsigned v = (unsigned)u << 16;
  return __builtin_bit_cast(float, v);
}
__device__ __forceinline__ unsigned pk2bf(float a, float b) {
  return (unsigned)f2bf(a) | ((unsigned)f2bf(b) << 16);
}

// K element (bh, spos, d) -> offset in KV-tiled layout (ushort units).
// Tile = 32 keys, 32KB: [K: kt(2)][d8(8)][ll(16)][lg(4)][e(8)] then V 16KB.
__device__ __forceinline__ size_t kaddr(int bh, int spos, int d) {
  return ((size_t)(bh * 64 + (spos >> 5))) * 16384
       + ((spos >> 4) & 1) * 4096 + (d >> 5) * 512 + (spos & 15) * 32
       + ((d >> 3) & 3) * 8 + (d & 7);
}

// ---------- K1: gates (ig/fg) + bf16 Q copy + K tiled copy ------------------
__global__ __launch_bounds__(512)
void gates_kernel(const float* __restrict__ q, const float* __restrict__ k,
                  const float* __restrict__ v,
                  const float* __restrict__ wi, const float* __restrict__ bi,
                  const float* __restrict__ wf, const float* __restrict__ bf,
                  float* __restrict__ ig, float* __restrict__ fg,
                  unsigned short* __restrict__ Qb, unsigned short* __restrict__ KVt)
{
  const int w = threadIdx.x >> 6, l = threadIdx.x & 63;
  const int bs0 = blockIdx.x * 16;
  const int bsr0 = bs0 + w * 2, bsr1 = bsr0 + 1;
  float p[2][8];
#pragma unroll
  for (int rr = 0; rr < 2; ++rr)
#pragma unroll
    for (int g2 = 0; g2 < 8; ++g2) p[rr][g2] = 0.f;

#pragma unroll
  for (int chunk = 0; chunk < 12; ++chunk) {
    const int idx = l * 4 + chunk * 256;     // 0..3071
    const float* src; int off;
    if (idx < 1024)       { src = q; off = idx; }
    else if (idx < 2048)  { src = k; off = idx - 1024; }
    else                  { src = v; off = idx - 2048; }
    float4 g0 = *(const float4*)(src + (size_t)bsr0 * Hx + off);
    float4 g1 = *(const float4*)(src + (size_t)bsr1 * Hx + off);
#pragma unroll
    for (int h = 0; h < 4; ++h) {
      float4 wiv = *(const float4*)(wi + h * 3 * Hx + idx);
      float4 wfv = *(const float4*)(wf + h * 3 * Hx + idx);
      p[0][h]     += g0.x*wiv.x + g0.y*wiv.y + g0.z*wiv.z + g0.w*wiv.w;
      p[1][h]     += g1.x*wiv.x + g1.y*wiv.y + g1.z*wiv.z + g1.w*wiv.w;
      p[0][4 + h] += g0.x*wfv.x + g0.y*wfv.y + g0.z*wfv.z + g0.w*wfv.w;
      p[1][4 + h] += g1.x*wfv.x + g1.y*wfv.y + g1.z*wfv.z + g1.w*wfv.w;
    }
    if (idx < 2048) {
      const int hh = off >> 8, dd = off & 255;
      const int b0 = bsr0 >> 11, s0p = bsr0 & 2047;
      const int b1 = bsr1 >> 11, s1p = bsr1 & 2047;
      ushort4 o0; o0.x=f2bf(g0.x); o0.y=f2bf(g0.y); o0.z=f2bf(g0.z); o0.w=f2bf(g0.w);
      ushort4 o1; o1.x=f2bf(g1.x); o1.y=f2bf(g1.y); o1.z=f2bf(g1.z); o1.w=f2bf(g1.w);
      if (idx < 1024) {
        *(ushort4*)(Qb + ((size_t)(b0 * NHx + hh) * Sx + s0p) * DHx + dd) = o0;
        *(ushort4*)(Qb + ((size_t)(b1 * NHx + hh) * Sx + s1p) * DHx + dd) = o1;
      } else {
        *(ushort4*)(KVt + kaddr(b0 * NHx + hh, s0p, dd)) = o0;
        *(ushort4*)(KVt + kaddr(b1 * NHx + hh, s1p, dd)) = o1;
      }
    }
  }
#pragma unroll
  for (int rr = 0; rr < 2; ++rr)
#pragma unroll
    for (int g2 = 0; g2 < 8; ++g2) {
      float x = p[rr][g2];
      x += __shfl_xor(x, 1);  x += __shfl_xor(x, 2);  x += __shfl_xor(x, 4);
      x += __shfl_xor(x, 8);  x += __shfl_xor(x, 16); x += __shfl_xor(x, 32);
      p[rr][g2] = x;
    }
  if (l == 0) {
#pragma unroll
    for (int rr = 0; rr < 2; ++rr) {
      const int bs = bs0 + w * 2 + rr;
      const int b = bs >> 11, spos = bs & 2047;
#pragma unroll
      for (int h = 0; h < 4; ++h) {
        ig[(size_t)(b * NHx + h) * Sx + spos] = p[rr][h] + bi[h];
        fg[(size_t)(b * NHx + h) * Sx + spos] = p[rr][4 + h] + bf[h];
      }
    }
  }
}

// ---------- K2: per-(b,h) scan: a[], M[], exp(-m)[] -------------------------
__global__ __launch_bounds__(256)
void scan_kernel(const float* __restrict__ ig, const float* __restrict__ fg,
                 float* __restrict__ av, float* __restrict__ Mv,
                 float* __restrict__ nfv)
{
  const int bh = blockIdx.x;
  const int t  = threadIdx.x;
  const size_t base = (size_t)bh * Sx;
  const int s0 = t * 8;
  float4 f0 = *(const float4*)(fg + base + s0);
  float4 f1 = *(const float4*)(fg + base + s0 + 4);
  float4 g0 = *(const float4*)(ig + base + s0);
  float4 g1 = *(const float4*)(ig + base + s0 + 4);
  float xf[8] = {f0.x,f0.y,f0.z,f0.w,f1.x,f1.y,f1.z,f1.w};
  float xi[8] = {g0.x,g0.y,g0.z,g0.w,g1.x,g1.y,g1.z,g1.w};
  float ps[8];
  float run = 0.0f;
#pragma unroll
  for (int i = 0; i < 8; ++i) { run += logsigf(xf[i]); ps[i] = run; }
  __shared__ float ssum[256];
  __shared__ float smax[256];
  ssum[t] = run;
  __syncthreads();
  for (int st = 1; st < 256; st <<= 1) {
    float addv = (t >= st) ? ssum[t - st] : 0.0f;
    __syncthreads();
    ssum[t] += addv;
    __syncthreads();
  }
  const float exs = (t > 0) ? ssum[t - 1] : 0.0f;
  float a[8], pm[8];
  float rm = -INFINITY;
#pragma unroll
  for (int i = 0; i < 8; ++i) {
    a[i] = xi[i] - (exs + ps[i]);
    rm = fmaxf(rm, a[i]);
    pm[i] = rm;
  }
  smax[t] = rm;
  __syncthreads();
  for (int st = 1; st < 256; st <<= 1) {
    float mv = (t >= st) ? smax[t - st] : -INFINITY;
    __syncthreads();
    smax[t] = fmaxf(smax[t], mv);
    __syncthreads();
  }
  const float exm = (t > 0) ? smax[t - 1] : -INFINITY;
#pragma unroll
  for (int i = 0; i < 8; ++i) {
    const float M = fmaxf(exm, pm[i]);
    const float F = exs + ps[i];
    av[base + s0 + i]  = a[i];
    Mv[base + s0 + i]  = M;
    nfv[base + s0 + i] = expf(-(F + M));
  }
}

// ---------- K3: V -> tiled bf16 fragment layout into KVt --------------------
// V part of tile: [ds2(16)][ll=d&15(16)][key_local(32)] ushorts at +8192.
__global__ __launch_bounds__(256)
void vtrans_kernel(const float* __restrict__ v, unsigned short* __restrict__ KVt)
{
  __shared__ float t32[32][260];
  const int tile = blockIdx.x, bh = blockIdx.y, b = bh >> 2, h = bh & 3;
  const int t = threadIdx.x;
  {
    const int r = t >> 3, dc = (t & 7) * 32;
    const float* p = v + ((size_t)b * Sx + tile * 32 + r) * Hx + h * DHx + dc;
#pragma unroll
    for (int i = 0; i < 8; ++i) {
      float4 x = *(const float4*)(p + i * 4);
      t32[r][dc + i*4 + 0] = x.x; t32[r][dc + i*4 + 1] = x.y;
      t32[r][dc + i*4 + 2] = x.z; t32[r][dc + i*4 + 3] = x.w;
    }
  }
  __syncthreads();
  {
    const int ds2 = t >> 4, llv = t & 15;
    const int d = ds2 * 16 + llv;
    unsigned short* dst = KVt + ((size_t)(bh * 64 + tile)) * 16384 + 8192
                        + ds2 * 512 + llv * 32;
#pragma unroll
    for (int g = 0; g < 8; ++g) {
      ushort4 o;
      o.x = f2bf(t32[g*4+0][d]); o.y = f2bf(t32[g*4+1][d]);
      o.z = f2bf(t32[g*4+2][d]); o.w = f2bf(t32[g*4+3][d]);
      *(ushort4*)(dst + g * 4) = o;
    }
  }
}

// ---------- K4a: pass1 — BQ=128 flash, T3/T4 pipelined LDS staging ----------
// 512 thr = 8 waves; wave owns 16 q-rows (R8 swapped-QK, lane-local P).
// Unit = (bh, ti 0..15, chunk 0/1): ntc = 2ti+2 key-tiles of 32.
// KV tile (32KB, fragment-ordered) staged global->reg->LDS, double-buffered,
// raw s_barrier + explicit waitcnt (NO __syncthreads drain in loop).
__global__ __launch_bounds__(512, 2)
void mlstm_pass1(const unsigned short* __restrict__ Qb,
                 const unsigned short* __restrict__ KVt,
                 const float* __restrict__ av, const float* __restrict__ Mv,
                 unsigned short* __restrict__ part, float* __restrict__ rsums)
{
  __shared__ __align__(16) unsigned short KVls[2][16384];  // 64 KB
  __shared__ float avls[1024];                             // 4 KB

  const int bh = blockIdx.x;
  const int u  = blockIdx.y;
  const int ti = 15 - (u >> 1), c = u & 1;
  const int i0 = ti * 128;
  const int ntc = 2 * ti + 2;
  const int tj0 = c * ntc, tje = tj0 + ntc;
  const int key0 = tj0 * 32;
  const int pidx = bh * 32 + u;

  const int tid = threadIdx.x;
  const int w = tid >> 6, l = tid & 63;
  const int lg = l >> 4, ll = l & 15;
  const size_t bhS = (size_t)bh * Sx;
  const int qrow = i0 + w * 16 + ll;

  // av preload into LDS (read via lgkm, keeps vmcnt clean in loop)
  for (int i = tid; i < ntc * 32; i += 512) avls[i] = av[bhS + key0 + i];

  // Q B-frags for this wave's 16 q-rows
  bf16x8 qf[8];
  {
    const unsigned short* qp = Qb + (bhS + qrow) * DHx + lg * 8;
#pragma unroll
    for (int d8 = 0; d8 < 8; ++d8) qf[d8] = *(const bf16x8*)(qp + d8 * 32);
  }
  const float Mq = Mv[bhS + qrow];

  f32x4 acc[16];
#pragma unroll
  for (int jt = 0; jt < 16; ++jt) acc[jt] = f32x4{0, 0, 0, 0};
  float rsum = 0.f;

  const unsigned short* kvb = KVt + (size_t)(bh * 64) * 16384;
  uint4 r0, r1, r2, r3;

#define LOADR(tj) {                                                        \
    const unsigned short* _s = kvb + (size_t)(tj) * 16384 + tid * 8;       \
    r0 = *(const uint4*)(_s);          r1 = *(const uint4*)(_s + 4096);    \
    r2 = *(const uint4*)(_s + 8192);   r3 = *(const uint4*)(_s + 12288); }
#define WRITER(buf) {                                                      \
    char* _d = (char*)&KVls[buf][0] + tid * 16;                            \
    *(uint4*)(_d)         = r0; *(uint4*)(_d + 8192)  = r1;                \
    *(uint4*)(_d + 16384) = r2; *(uint4*)(_d + 24576) = r3; }

  LOADR(tj0);
  asm volatile("s_waitcnt vmcnt(0)" ::: "memory");
  WRITER(0);
  LOADR(tj0 + 1);                       // ntc >= 2 always
  asm volatile("s_waitcnt lgkmcnt(0)" ::: "memory");
  __builtin_amdgcn_s_barrier();

  for (int tj = tj0; tj < tje; ++tj) {
    const int cur = (tj - tj0) & 1;
    // r holds tile tj+1 (issued last iter) — hidden under previous compute
    asm volatile("s_waitcnt vmcnt(0)" ::: "memory");
    if (tj + 1 < tje) WRITER(cur ^ 1);          // stage tj+1 into other buf
    if (tj + 2 < tje) LOADR(tj + 2);            // issue next loads (in flight)
    __builtin_amdgcn_sched_barrier(0);

    const char* KB = (const char*)&KVls[cur][0];
    const char* VB = KB + 16384;
    const int rel = tj * 32 - key0;

    // ---- QK: two 16-key subtiles, conflict-free contiguous b128 reads ----
    f32x4 st0 = {0,0,0,0}, st1 = {0,0,0,0};
#pragma unroll
    for (int d8 = 0; d8 < 8; ++d8) {
      const int fo = d8 * 1024 + ll * 64 + lg * 16;
      bf16x8 k0 = *(const bf16x8*)(KB + fo);
      bf16x8 k1 = *(const bf16x8*)(KB + 8192 + fo);
      st0 = __builtin_amdgcn_mfma_f32_16x16x32_bf16(k0, qf[d8], st0, 0, 0, 0);
      st1 = __builtin_amdgcn_mfma_f32_16x16x32_bf16(k1, qf[d8], st1, 0, 0, 0);
    }
    const f32x4 a4_0 = *(const f32x4*)&avls[rel + lg * 4];
    const f32x4 a4_1 = *(const f32x4*)&avls[rel + 16 + lg * 4];

    // ---- transform: mask + decay + rsum; pack bf16; lane redistribution ----
    const int j0 = tj * 32;
    unsigned x0[4], x1[4];
#pragma unroll
    for (int kt = 0; kt < 2; ++kt) {
      const f32x4 s = kt ? st1 : st0;
      const f32x4 a = kt ? a4_1 : a4_0;
      const int kb = j0 + kt * 16 + 4 * lg;
      float p0 = (kb + 0 <= qrow) ? s[0] * (RSQ * __expf(a[0] - Mq)) : 0.f;
      float p1 = (kb + 1 <= qrow) ? s[1] * (RSQ * __expf(a[1] - Mq)) : 0.f;
      float p2 = (kb + 2 <= qrow) ? s[2] * (RSQ * __expf(a[2] - Mq)) : 0.f;
      float p3 = (kb + 3 <= qrow) ? s[3] * (RSQ * __expf(a[3] - Mq)) : 0.f;
      rsum += (p0 + p1) + (p2 + p3);
      unsigned lo = pk2bf(p0, p1), hi = pk2bf(p2, p3);
      unsigned plo = __shfl_xor(lo, 16), phi = __shfl_xor(hi, 16);
      bool ge = ((lg & 1) == 0);
      unsigned* x = kt ? x1 : x0;
      x[0] = ge ? lo : plo;  x[1] = ge ? hi : phi;
      x[2] = ge ? plo : lo;  x[3] = ge ? phi : hi;
    }
    unsigned pw0, pw1, pw2, pw3;
#pragma unroll
    for (int j = 0; j < 4; ++j) {
      unsigned yA = __shfl_xor(x0[j], 32);
      unsigned yB = __shfl_xor(x1[j], 32);
      unsigned r = (lg == 0) ? x0[j] : (lg == 1) ? yA : (lg == 2) ? yB : x1[j];
      if (j == 0) pw0 = r; else if (j == 1) pw1 = r; else if (j == 2) pw2 = r; else pw3 = r;
    }
    u32x4 w4 = {pw0, pw1, pw2, pw3};
    bf16x8 pb = __builtin_bit_cast(bf16x8, w4);

    // ---- PV: 16 d-subtiles, full D per wave ----
#pragma unroll
    for (int ds2 = 0; ds2 < 16; ++ds2) {
      bf16x8 vf = *(const bf16x8*)(VB + ds2 * 1024 + ll * 64 + lg * 16);
      acc[ds2] = __builtin_amdgcn_mfma_f32_16x16x32_bf16(vf, pb, acc[ds2], 0, 0, 0);
    }

    asm volatile("s_waitcnt lgkmcnt(0)" ::: "memory");
    __builtin_amdgcn_sched_barrier(0);
    __builtin_amdgcn_s_barrier();
  }
#undef LOADR
#undef WRITER

  // ---- epilogue: bf16 partial O + f32 rsum ----
  float rs = rsum;
  rs += __shfl_xor(rs, 16); rs += __shfl_xor(rs, 32);
  unsigned short* pO = part + (size_t)pidx * 32768 + (w * 16 + ll) * 256 + lg * 4;
#pragma unroll
  for (int ds2 = 0; ds2 < 16; ++ds2) {
    ushort4 o;
    o.x = f2bf(acc[ds2][0]); o.y = f2bf(acc[ds2][1]);
    o.z = f2bf(acc[ds2][2]); o.w = f2bf(acc[ds2][3]);
    *(ushort4*)(pO + ds2 * 16) = o;
  }
  if (lg == 0) rsums[pidx * 128 + w * 16 + ll] = rs;
}

// ---------- K4b: pass2 — combine 2 chunks + normalizer + group-LN -----------
__global__ __launch_bounds__(512)
void mlstm_pass2(const unsigned short* __restrict__ part,
                 const float* __restrict__ rsums,
                 const float* __restrict__ nfv, const float* __restrict__ lnw,
                 float* __restrict__ out)
{
  const int bh = blockIdx.x, b = bh >> 2, h = bh & 3;
  const int ti = blockIdx.y;
  const int u0 = (15 - ti) * 2;
  const int p0 = bh * 32 + u0, p1 = p0 + 1;
  const int tid = threadIdx.x;
  const int q = tid >> 2, dc = (tid & 3) * 64;
  const int qrow = ti * 128 + q;
  const size_t bhS = (size_t)bh * Sx;

  const unsigned short* A  = part + (size_t)p0 * 32768 + q * 256 + dc;
  const unsigned short* Bp = part + (size_t)p1 * 32768 + q * 256 + dc;
  const float rs = rsums[p0 * 128 + q] + rsums[p1 * 128 + q];
  const float nf = nfv[bhS + qrow];
  const float inv = 1.f / (fmaxf(fabsf(rs), nf) + 1e-6f);

  float o[64];
  float s1 = 0.f, s2 = 0.f;
#pragma unroll
  for (int j = 0; j < 8; ++j) {
    bf16x8 va = *(const bf16x8*)(A + j * 8);
    bf16x8 vb = *(const bf16x8*)(Bp + j * 8);
#pragma unroll
    for (int r = 0; r < 8; ++r) {
      float x = (bf2f((unsigned short)va[r]) + bf2f((unsigned short)vb[r])) * inv;
      o[j * 8 + r] = x; s1 += x; s2 += x * x;
    }
  }
  s1 += __shfl_xor(s1, 1); s1 += __shfl_xor(s1, 2);
  s2 += __shfl_xor(s2, 1); s2 += __shfl_xor(s2, 2);
  const float mean = s1 * (1.f / 256.f);
  const float var  = s2 * (1.f / 256.f) - mean * mean;
  const float rstd = rsqrtf(var + 1e-5f);
  float* op = out + ((size_t)b * Sx + qrow) * Hx + h * DHx + dc;
#pragma unroll
  for (int j = 0; j < 16; ++j) {
    f32x4 lw = *(const f32x4*)(lnw + h * DHx + dc + j * 4);
    float4 ov;
    ov.x = (o[j*4+0] - mean) * rstd * (1.f + lw[0]);
    ov.y = (o[j*4+1] - mean) * rstd * (1.f + lw[1]);
    ov.z = (o[j*4+2] - mean) * rstd * (1.f + lw[2]);
    ov.w = (o[j*4+3] - mean) * rstd * (1.f + lw[3]);
    *(float4*)(op + j * 4) = ov;
  }
}

extern "C" void kernel_launch(void* const* d_in, const int* in_sizes, int n_in,
                              void* d_out, int out_size, void* d_ws, size_t ws_size,
                              hipStream_t stream) {
  const float* q   = (const float*)d_in[0];
  const float* k   = (const float*)d_in[1];
  const float* v   = (const float*)d_in[2];
  const float* wi  = (const float*)d_in[3];
  const float* bi  = (const float*)d_in[4];
  const float* wf  = (const float*)d_in[5];
  const float* bf  = (const float*)d_in[6];
  const float* lnw = (const float*)d_in[7];
  float* out = (float*)d_out;
  float* ws  = (float*)d_ws;

  const int G = Bx * NHx * Sx;         // 16384
  float* ig  = ws;
  float* fg  = ws + (size_t)G;
  float* av  = ws + (size_t)2 * G;
  float* Mv  = ws + (size_t)3 * G;
  float* nfv = ws + (size_t)4 * G;
  unsigned short* Qb   = (unsigned short*)(ws + (size_t)5 * G);  // 16 MB
  unsigned short* KVt  = Qb + (size_t)8388608;                   // 16 MB tiled KV
  unsigned short* part = KVt + (size_t)8388608;                  // 16 MB partials
  float* rsums = (float*)(part + (size_t)8388608);               // 128 KB
  // total ws use: ~48.5 MB

  gates_kernel<<<Bx * Sx / 16, 512, 0, stream>>>(q, k, v, wi, bi, wf, bf, ig, fg, Qb, KVt);
  scan_kernel<<<Bx * NHx, 256, 0, stream>>>(ig, fg, av, Mv, nfv);
  dim3 gT(64, Bx * NHx);
  vtrans_kernel<<<gT, 256, 0, stream>>>(v, KVt);
  dim3 g1(Bx * NHx, 32);               // x = bh (XCD pinned), y = unit (LPT)
  mlstm_pass1<<<g1, 512, 0, stream>>>(Qb, KVt, av, Mv, part, rsums);
  dim3 g2(Bx * NHx, 16);
  mlstm_pass2<<<g2, 512, 0, stream>>>(part, rsums, nfv, lnw, out);
}